// Round 2
// baseline (382.853 us; speedup 1.0000x reference)
//
#include <hip/hip_runtime.h>

typedef unsigned short u16;
typedef unsigned int   u32;
typedef __attribute__((ext_vector_type(8)))  __bf16 bf16x8;
typedef __attribute__((ext_vector_type(16))) float  f32x16;

#define PDIM 258
#define NIMG 16

static __device__ __forceinline__ u16 f2bf(float f) {
  u32 u = __builtin_bit_cast(u32, f);
  u32 r = u + 0x7FFFu + ((u >> 16) & 1u);
  return (u16)(r >> 16);
}

// DWT: x (16,3,512,512) f32 -> hi_g [16][258][258][16] bf16 (ch 0..8 = LH,HL,HH x3; rest 0)
//                              lo_g [16][258][258][4]  bf16 (ch 0..2 = LL; rest 0)
// 1-pixel zero border = conv zero padding.
__global__ void dwt_kernel(const float* __restrict__ x,
                           u16* __restrict__ hi_g, u16* __restrict__ lo_g) {
  int t = blockIdx.x * 256 + threadIdx.x;
  if (t >= NIMG * PDIM * PDIM) return;        // 1,065,024 total (round-1 bug: grid was short 576)
  int px = t % PDIM;
  int ty = t / PDIM;
  int py = ty % PDIM;
  int n  = ty / PDIM;

  u16 hc[16];
  u16 lc[4];
  if (px == 0 || px == PDIM - 1 || py == 0 || py == PDIM - 1) {
#pragma unroll
    for (int i = 0; i < 16; ++i) hc[i] = 0;
#pragma unroll
    for (int i = 0; i < 4; ++i) lc[i] = 0;
  } else {
    int oh = py - 1, ow = px - 1;
#pragma unroll
    for (int c = 0; c < 3; ++c) {
      const float* bp = x + (((size_t)(n * 3 + c) * 512 + 2 * oh) * 512 + 2 * ow);
      float2 r0 = *(const float2*)bp;
      float2 r1 = *(const float2*)(bp + 512);
      float a = r0.x, b = r0.y, cc = r1.x, d = r1.y;
      hc[c]     = f2bf((a + b - cc - d) * 0.5f);   // LH
      hc[3 + c] = f2bf((a - b + cc - d) * 0.5f);   // HL
      hc[6 + c] = f2bf((a - b - cc + d) * 0.5f);   // HH
      lc[c]     = f2bf((a + b + cc + d) * 0.5f);   // LL
    }
#pragma unroll
    for (int i = 9; i < 16; ++i) hc[i] = 0;
    lc[3] = 0;
  }
  u32 wds[8];
#pragma unroll
  for (int i = 0; i < 8; ++i) wds[i] = (u32)hc[2 * i] | ((u32)hc[2 * i + 1] << 16);
  uint4 q0; q0.x = wds[0]; q0.y = wds[1]; q0.z = wds[2]; q0.w = wds[3];
  uint4 q1; q1.x = wds[4]; q1.y = wds[5]; q1.z = wds[6]; q1.w = wds[7];
  uint4* hp = (uint4*)(hi_g + (size_t)t * 16);
  hp[0] = q0; hp[1] = q1;
  uint2 ql; ql.x = (u32)lc[0] | ((u32)lc[1] << 16); ql.y = (u32)lc[2] | ((u32)lc[3] << 16);
  *(uint2*)(lo_g + (size_t)t * 4) = ql;
}

// High conv: Cin=9 (padded 16), 3x3, Cout=64 over (16,256,256).
// Block: 512 thr = 8 waves; tile = 8 oh x 32 ow; wave w owns oh row ohb+w, all 64 cout.
// MFMA 32x32x16 bf16, K = 9 taps x 16ch.
// MODE 0: accumulate per-channel sum/sumsq into gstats[0..127].
// MODE 1: apply scale/shift (+ReLU) and store; operand-swapped so stores coalesce on ow.
template <int MODE>
__global__ __launch_bounds__(512) void conv_hi(const u16* __restrict__ in_g,
                                               const float* __restrict__ w_g,
                                               float* __restrict__ gstats,
                                               const float* __restrict__ scales,
                                               float* __restrict__ out) {
  __shared__ __align__(16) u16 lin[10 * 34 * 16];
  __shared__ __align__(16) u16 wt[64 * 144];
  __shared__ float red[128];
  int tid = threadIdx.x;
  int bx = blockIdx.x;
  int owb = (bx & 7) * 32;
  int ohb = ((bx >> 3) & 31) * 8;
  int n = bx >> 8;

  // stage weights: wt[co][tap*16 + c] (c>=9 zero)
  for (int i = tid; i < 64 * 144; i += 512) {
    int co = i / 144;
    int k = i - co * 144;
    int tap = k >> 4, c = k & 15;
    float v = 0.f;
    if (c < 9) v = w_g[((co * 9 + c) * 3 + tap / 3) * 3 + (tap % 3)];
    wt[i] = f2bf(v);
  }
  // stage input tile: 10 rows x 34 cells x 32B (rows contiguous in global too)
  {
    const u16* src = in_g + (size_t)n * (PDIM * PDIM * 16);
    for (int i = tid; i < 680; i += 512) {
      int r = i / 68;
      int o = i - r * 68;
      const uint4* g = (const uint4*)(src + ((size_t)(ohb + r) * PDIM + owb) * 16) + o;
      ((uint4*)lin)[i] = *g;
    }
  }
  if constexpr (MODE == 0) {
    if (tid < 128) red[tid] = 0.f;
  } else {
    if (tid < 128) red[tid] = scales[tid];   // [0..63]=scale, [64..127]=shift
  }
  __syncthreads();

  int w = tid >> 6;
  int l = tid & 63;
  int m = l & 31;
  int h2 = l >> 5;
  f32x16 acc0, acc1;
#pragma unroll
  for (int i = 0; i < 16; ++i) { acc0[i] = 0.f; acc1[i] = 0.f; }

#pragma unroll
  for (int g = 0; g < 9; ++g) {
    int kh = g / 3, kw = g - kh * 3;
    bf16x8 a  = *(const bf16x8*)&lin[((w + kh) * 34 + m + kw) * 16 + h2 * 8];
    bf16x8 b0 = *(const bf16x8*)&wt[m * 144 + g * 16 + h2 * 8];
    bf16x8 b1 = *(const bf16x8*)&wt[(32 + m) * 144 + g * 16 + h2 * 8];
    if constexpr (MODE == 0) {
      acc0 = __builtin_amdgcn_mfma_f32_32x32x16_bf16(a, b0, acc0, 0, 0, 0);
      acc1 = __builtin_amdgcn_mfma_f32_32x32x16_bf16(a, b1, acc1, 0, 0, 0);
    } else {
      acc0 = __builtin_amdgcn_mfma_f32_32x32x16_bf16(b0, a, acc0, 0, 0, 0);
      acc1 = __builtin_amdgcn_mfma_f32_32x32x16_bf16(b1, a, acc1, 0, 0, 0);
    }
  }

  if constexpr (MODE == 0) {
    // D rows = positions, cols = cout: lane's cout is nt*32 + m for all regs
    float ps0 = 0, pq0 = 0, ps1 = 0, pq1 = 0;
#pragma unroll
    for (int i = 0; i < 16; ++i) {
      ps0 += acc0[i]; pq0 += acc0[i] * acc0[i];
      ps1 += acc1[i]; pq1 += acc1[i] * acc1[i];
    }
    ps0 += __shfl_xor(ps0, 32); pq0 += __shfl_xor(pq0, 32);
    ps1 += __shfl_xor(ps1, 32); pq1 += __shfl_xor(pq1, 32);
    if (h2 == 0) {
      atomicAdd(&red[m], ps0);
      atomicAdd(&red[32 + m], ps1);
      atomicAdd(&red[64 + m], pq0);
      atomicAdd(&red[96 + m], pq1);
    }
    __syncthreads();
    if (tid < 128) atomicAdd(&gstats[tid], red[tid]);
  } else {
    // D rows = cout, cols = positions: col = m = ow offset -> coalesced stores
    float* op = out + (size_t)n * 64 * 65536 + (size_t)(ohb + w) * 256 + owb + m;
#pragma unroll
    for (int r = 0; r < 16; ++r) {
      int row = (r & 3) + 8 * (r >> 2) + 4 * h2;
      float v0 = acc0[r] * red[row] + red[64 + row];
      op[(size_t)row * 65536] = v0 > 0.f ? v0 : 0.f;
      float v1 = acc1[r] * red[32 + row] + red[96 + row];
      op[(size_t)(32 + row) * 65536] = v1 > 0.f ? v1 : 0.f;
    }
  }
}

// Low conv: Cin=3 (padded to 8 in LDS, 4 in global), 3x3, Cout=64.
// K = 6 groups of 16: g=(kh,kwp), k = j*8+c with kw=kwp*2+j (kw=3 / c>=3 -> zero weight).
template <int MODE>
__global__ __launch_bounds__(512) void conv_lo(const u16* __restrict__ in_g,
                                               const float* __restrict__ w_g,
                                               float* __restrict__ gstats,
                                               const float* __restrict__ scales,
                                               float* __restrict__ out) {
  __shared__ __align__(16) u16 lin[10 * 35 * 8];
  __shared__ __align__(16) u16 wt[64 * 96];
  __shared__ float red[128];
  int tid = threadIdx.x;
  int bx = blockIdx.x;
  int owb = (bx & 7) * 32;
  int ohb = ((bx >> 3) & 31) * 8;
  int n = bx >> 8;

  for (int i = tid; i < 64 * 96; i += 512) {
    int co = i / 96;
    int k = i - co * 96;
    int g = k >> 4, j = (k >> 3) & 1, c = k & 7;
    int kh = g >> 1, kw = (g & 1) * 2 + j;
    float v = 0.f;
    if (c < 3 && kw < 3) v = w_g[((co * 3 + c) * 3 + kh) * 3 + kw];
    wt[i] = f2bf(v);
  }
  {
    const u16* src = in_g + (size_t)n * (PDIM * PDIM * 4);
    uint2 z; z.x = 0; z.y = 0;
    for (int i = tid; i < 350; i += 512) {
      int r = i / 35;
      int cx = i - r * 35;
      int gx = owb + cx;
      uint2 v = z;
      if (gx < PDIM) v = *(const uint2*)(src + ((size_t)(ohb + r) * PDIM + gx) * 4);
      *(uint2*)&lin[(r * 35 + cx) * 8] = v;       // ch 0..3
      *(uint2*)&lin[(r * 35 + cx) * 8 + 4] = z;   // ch 4..7 = 0
    }
  }
  if constexpr (MODE == 0) {
    if (tid < 128) red[tid] = 0.f;
  } else {
    if (tid < 128) red[tid] = scales[tid];
  }
  __syncthreads();

  int w = tid >> 6;
  int l = tid & 63;
  int m = l & 31;
  int h2 = l >> 5;
  f32x16 acc0, acc1;
#pragma unroll
  for (int i = 0; i < 16; ++i) { acc0[i] = 0.f; acc1[i] = 0.f; }

#pragma unroll
  for (int g = 0; g < 6; ++g) {
    int kh = g >> 1, kwp = g & 1;
    bf16x8 a  = *(const bf16x8*)&lin[((w + kh) * 35 + m + kwp * 2 + h2) * 8];
    bf16x8 b0 = *(const bf16x8*)&wt[m * 96 + g * 16 + h2 * 8];
    bf16x8 b1 = *(const bf16x8*)&wt[(32 + m) * 96 + g * 16 + h2 * 8];
    if constexpr (MODE == 0) {
      acc0 = __builtin_amdgcn_mfma_f32_32x32x16_bf16(a, b0, acc0, 0, 0, 0);
      acc1 = __builtin_amdgcn_mfma_f32_32x32x16_bf16(a, b1, acc1, 0, 0, 0);
    } else {
      acc0 = __builtin_amdgcn_mfma_f32_32x32x16_bf16(b0, a, acc0, 0, 0, 0);
      acc1 = __builtin_amdgcn_mfma_f32_32x32x16_bf16(b1, a, acc1, 0, 0, 0);
    }
  }

  if constexpr (MODE == 0) {
    float ps0 = 0, pq0 = 0, ps1 = 0, pq1 = 0;
#pragma unroll
    for (int i = 0; i < 16; ++i) {
      ps0 += acc0[i]; pq0 += acc0[i] * acc0[i];
      ps1 += acc1[i]; pq1 += acc1[i] * acc1[i];
    }
    ps0 += __shfl_xor(ps0, 32); pq0 += __shfl_xor(pq0, 32);
    ps1 += __shfl_xor(ps1, 32); pq1 += __shfl_xor(pq1, 32);
    if (h2 == 0) {
      atomicAdd(&red[m], ps0);
      atomicAdd(&red[32 + m], ps1);
      atomicAdd(&red[64 + m], pq0);
      atomicAdd(&red[96 + m], pq1);
    }
    __syncthreads();
    if (tid < 128) atomicAdd(&gstats[tid], red[tid]);
  } else {
    float* op = out + (size_t)n * 64 * 65536 + (size_t)(ohb + w) * 256 + owb + m;
#pragma unroll
    for (int r = 0; r < 16; ++r) {
      int row = (r & 3) + 8 * (r >> 2) + 4 * h2;
      float v0 = acc0[r] * red[row] + red[64 + row];
      op[(size_t)row * 65536] = v0 > 0.f ? v0 : 0.f;
      float v1 = acc1[r] * red[32 + row] + red[96 + row];
      op[(size_t)(32 + row) * 65536] = v1 > 0.f ? v1 : 0.f;
    }
  }
}

// stats -> scale/shift. Conv bias cancels inside training-mode BN, so it is ignored.
__global__ void finalize_kernel(const float* __restrict__ gs,
                                const float* __restrict__ hgam, const float* __restrict__ hbet,
                                const float* __restrict__ lgam, const float* __restrict__ lbet,
                                float* __restrict__ sc) {
  int t = threadIdx.x;   // 128 threads
  const float invP = 1.0f / 1048576.0f;   // 16*256*256
  if (t < 64) {
    float mean = gs[t] * invP;
    float var = gs[64 + t] * invP - mean * mean;
    float s = hgam[t] * rsqrtf(var + 1e-5f);
    sc[t] = s;
    sc[64 + t] = hbet[t] - mean * s;
  } else {
    int c = t - 64;
    float mean = gs[128 + c] * invP;
    float var = gs[192 + c] * invP - mean * mean;
    float s = lgam[c] * rsqrtf(var + 1e-5f);
    sc[128 + c] = s;
    sc[192 + c] = lbet[c] - mean * s;
  }
}

extern "C" void kernel_launch(void* const* d_in, const int* in_sizes, int n_in,
                              void* d_out, int out_size, void* d_ws, size_t ws_size,
                              hipStream_t stream) {
  const float* x    = (const float*)d_in[0];
  const float* hw   = (const float*)d_in[1];
  const float* hgam = (const float*)d_in[3];
  const float* hbet = (const float*)d_in[4];
  const float* lw   = (const float*)d_in[5];
  const float* lgam = (const float*)d_in[7];
  const float* lbet = (const float*)d_in[8];
  float* out = (float*)d_out;
  float* wsf = (float*)d_ws;

  // ws layout: [0,2048) stats+scales | hi_g 34,080,768 B | lo_g 8,520,192 B  (total ~42.6 MB)
  u16* hi_g = (u16*)((char*)d_ws + 2048);
  u16* lo_g = (u16*)((char*)d_ws + 2048 + (size_t)NIMG * PDIM * PDIM * 16 * 2);

  hipMemsetAsync(d_ws, 0, 2048, stream);   // zero stat accumulators

  int dwt_total = NIMG * PDIM * PDIM;                 // 1,065,024
  dwt_kernel<<<(dwt_total + 255) / 256, 256, 0, stream>>>(x, hi_g, lo_g);

  conv_hi<0><<<4096, 512, 0, stream>>>(hi_g, hw, wsf, nullptr, nullptr);
  conv_lo<0><<<4096, 512, 0, stream>>>(lo_g, lw, wsf + 128, nullptr, nullptr);

  finalize_kernel<<<1, 128, 0, stream>>>(wsf, hgam, hbet, lgam, lbet, wsf + 256);

  conv_hi<1><<<4096, 512, 0, stream>>>(hi_g, hw, nullptr, wsf + 256, out);
  conv_lo<1><<<4096, 512, 0, stream>>>(lo_g, lw, nullptr, wsf + 384,
                                       out + (size_t)NIMG * 64 * 65536);
}

// Round 3
// 211.244 us; speedup vs baseline: 1.8124x; 1.8124x over previous
//
#include <hip/hip_runtime.h>

typedef unsigned short u16;
typedef unsigned int   u32;
typedef __attribute__((ext_vector_type(8)))  __bf16 bf16x8;
typedef __attribute__((ext_vector_type(16))) float  f32x16;

#define PDIM 258
#define NIMG 16

static __device__ __forceinline__ u16 f2bf(float f) {
  u32 u = __builtin_bit_cast(u32, f);
  u32 r = u + 0x7FFFu + ((u >> 16) & 1u);
  return (u16)(r >> 16);
}

// ---------------------------------------------------------------------------
// Weight prep: convert to bf16 once, laid out in MFMA B-fragment order so conv
// blocks stage with a LINEAR copy and LDS reads are contiguous-1KB (no bank
// serialization; round-2 layout had 288B/192B lane strides -> 8/2 banks only).
// hi: e = (((g*2+h2)*2 + cohalf)*32 + m)*8 + t ; k = h2*8+t = cin (c<9 else 0)
// lo: same shape, g=(kh,kwp) 0..5; k = h2*8+t -> spatial j=h2, cin c=t
// ---------------------------------------------------------------------------
__global__ void prep_weights(const float* __restrict__ hw, const float* __restrict__ lw,
                             u16* __restrict__ wtg_hi, u16* __restrict__ wtg_lo) {
  int tid = threadIdx.x;
  for (int e = tid; e < 9216; e += 512) {
    int t  = e & 7;
    int m  = (e >> 3) & 31;
    int ch = (e >> 8) & 1;
    int gh = e >> 9;              // g*2 + h2, 0..17
    int h2 = gh & 1, g = gh >> 1;
    int c  = h2 * 8 + t;
    int co = ch * 32 + m;
    float v = 0.f;
    if (c < 9) v = hw[((co * 9 + c) * 3 + g / 3) * 3 + (g % 3)];
    wtg_hi[e] = f2bf(v);
  }
  for (int e = tid; e < 6144; e += 512) {
    int t  = e & 7;
    int m  = (e >> 3) & 31;
    int ch = (e >> 8) & 1;
    int gh = e >> 9;              // g*2 + h2, 0..11
    int h2 = gh & 1, g = gh >> 1;
    int kh = g >> 1, kw = (g & 1) * 2 + h2;
    int co = ch * 32 + m;
    float v = 0.f;
    if (t < 3 && kw < 3) v = lw[((co * 3 + t) * 3 + kh) * 3 + kw];
    wtg_lo[e] = f2bf(v);
  }
}

// DWT: x (16,3,512,512) f32 -> hi_g [16][258][258][16] bf16 (ch 0..8 = LH,HL,HH x3)
//                              lo_g [16][258][258][4]  bf16 (ch 0..2 = LL)
__global__ void dwt_kernel(const float* __restrict__ x,
                           u16* __restrict__ hi_g, u16* __restrict__ lo_g) {
  int t = blockIdx.x * 256 + threadIdx.x;
  if (t >= NIMG * PDIM * PDIM) return;
  int px = t % PDIM;
  int ty = t / PDIM;
  int py = ty % PDIM;
  int n  = ty / PDIM;

  u16 hc[16];
  u16 lc[4];
  if (px == 0 || px == PDIM - 1 || py == 0 || py == PDIM - 1) {
#pragma unroll
    for (int i = 0; i < 16; ++i) hc[i] = 0;
#pragma unroll
    for (int i = 0; i < 4; ++i) lc[i] = 0;
  } else {
    int oh = py - 1, ow = px - 1;
#pragma unroll
    for (int c = 0; c < 3; ++c) {
      const float* bp = x + (((size_t)(n * 3 + c) * 512 + 2 * oh) * 512 + 2 * ow);
      float2 r0 = *(const float2*)bp;
      float2 r1 = *(const float2*)(bp + 512);
      float a = r0.x, b = r0.y, cc = r1.x, d = r1.y;
      hc[c]     = f2bf((a + b - cc - d) * 0.5f);
      hc[3 + c] = f2bf((a - b + cc - d) * 0.5f);
      hc[6 + c] = f2bf((a - b - cc + d) * 0.5f);
      lc[c]     = f2bf((a + b + cc + d) * 0.5f);
    }
#pragma unroll
    for (int i = 9; i < 16; ++i) hc[i] = 0;
    lc[3] = 0;
  }
  u32 wds[8];
#pragma unroll
  for (int i = 0; i < 8; ++i) wds[i] = (u32)hc[2 * i] | ((u32)hc[2 * i + 1] << 16);
  uint4 q0; q0.x = wds[0]; q0.y = wds[1]; q0.z = wds[2]; q0.w = wds[3];
  uint4 q1; q1.x = wds[4]; q1.y = wds[5]; q1.z = wds[6]; q1.w = wds[7];
  uint4* hp = (uint4*)(hi_g + (size_t)t * 16);
  hp[0] = q0; hp[1] = q1;
  uint2 ql; ql.x = (u32)lc[0] | ((u32)lc[1] << 16); ql.y = (u32)lc[2] | ((u32)lc[3] << 16);
  *(uint2*)(lo_g + (size_t)t * 4) = ql;
}

// High conv: Cin=9 (pad 16), 3x3, Cout=64 over (16,256,256); 8 waves, 8oh x 32ow.
// MODE 0: per-channel sum/sumsq into gstats replica (bx&31). MODE 1: BN+ReLU store.
template <int MODE>
__global__ __launch_bounds__(512) void conv_hi(const u16* __restrict__ in_g,
                                               const u16* __restrict__ wtg,
                                               float* __restrict__ gstats,
                                               const float* __restrict__ scales,
                                               float* __restrict__ out) {
  __shared__ __align__(16) u16 lin[10 * 34 * 16];
  __shared__ __align__(16) u16 wt[9216];
  __shared__ float red[128];
  int tid = threadIdx.x;
  int bx = blockIdx.x;
  int owb = (bx & 7) * 32;
  int ohb = ((bx >> 3) & 31) * 8;
  int n = bx >> 8;

  // weights: linear 18KB copy (fragment order precomputed)
  {
    const uint4* src = (const uint4*)wtg;
    for (int i = tid; i < 1152; i += 512) ((uint4*)wt)[i] = src[i];
  }
  // input tile: 10 rows x 34 cells x 32B
  {
    const u16* src = in_g + (size_t)n * (PDIM * PDIM * 16);
    for (int i = tid; i < 680; i += 512) {
      int r = i / 68;
      int o = i - r * 68;
      const uint4* g = (const uint4*)(src + ((size_t)(ohb + r) * PDIM + owb) * 16) + o;
      ((uint4*)lin)[i] = *g;
    }
  }
  if constexpr (MODE == 0) {
    if (tid < 128) red[tid] = 0.f;
  } else {
    if (tid < 128) red[tid] = scales[tid];   // [0..63]=scale, [64..127]=shift
  }
  __syncthreads();

  int w = tid >> 6;
  int l = tid & 63;
  int m = l & 31;
  int h2 = l >> 5;
  f32x16 acc0, acc1;
#pragma unroll
  for (int i = 0; i < 16; ++i) { acc0[i] = 0.f; acc1[i] = 0.f; }

#pragma unroll
  for (int g = 0; g < 9; ++g) {
    int kh = g / 3, kw = g - kh * 3;
    bf16x8 a  = *(const bf16x8*)&lin[((w + kh) * 34 + m + kw) * 16 + h2 * 8];
    bf16x8 b0 = *(const bf16x8*)&wt[(2 * g + h2) * 512 + m * 8];
    bf16x8 b1 = *(const bf16x8*)&wt[(2 * g + h2) * 512 + 256 + m * 8];
    if constexpr (MODE == 0) {
      acc0 = __builtin_amdgcn_mfma_f32_32x32x16_bf16(a, b0, acc0, 0, 0, 0);
      acc1 = __builtin_amdgcn_mfma_f32_32x32x16_bf16(a, b1, acc1, 0, 0, 0);
    } else {
      acc0 = __builtin_amdgcn_mfma_f32_32x32x16_bf16(b0, a, acc0, 0, 0, 0);
      acc1 = __builtin_amdgcn_mfma_f32_32x32x16_bf16(b1, a, acc1, 0, 0, 0);
    }
  }

  if constexpr (MODE == 0) {
    float ps0 = 0, pq0 = 0, ps1 = 0, pq1 = 0;
#pragma unroll
    for (int i = 0; i < 16; ++i) {
      ps0 += acc0[i]; pq0 += acc0[i] * acc0[i];
      ps1 += acc1[i]; pq1 += acc1[i] * acc1[i];
    }
    ps0 += __shfl_xor(ps0, 32); pq0 += __shfl_xor(pq0, 32);
    ps1 += __shfl_xor(ps1, 32); pq1 += __shfl_xor(pq1, 32);
    if (h2 == 0) {
      atomicAdd(&red[m], ps0);
      atomicAdd(&red[32 + m], ps1);
      atomicAdd(&red[64 + m], pq0);
      atomicAdd(&red[96 + m], pq1);
    }
    __syncthreads();
    if (tid < 128) atomicAdd(&gstats[(bx & 31) * 128 + tid], red[tid]);
  } else {
    float* op = out + (size_t)n * 64 * 65536 + (size_t)(ohb + w) * 256 + owb + m;
#pragma unroll
    for (int r = 0; r < 16; ++r) {
      int row = (r & 3) + 8 * (r >> 2) + 4 * h2;
      float v0 = acc0[r] * red[row] + red[64 + row];
      __builtin_nontemporal_store(v0 > 0.f ? v0 : 0.f, op + (size_t)row * 65536);
      float v1 = acc1[r] * red[32 + row] + red[96 + row];
      __builtin_nontemporal_store(v1 > 0.f ? v1 : 0.f, op + (size_t)(32 + row) * 65536);
    }
  }
}

// Low conv: Cin=3 (pad 8), 3x3, Cout=64; K = 6 groups of 16 (j=h2 spatial, c=t).
template <int MODE>
__global__ __launch_bounds__(512) void conv_lo(const u16* __restrict__ in_g,
                                               const u16* __restrict__ wtg,
                                               float* __restrict__ gstats,
                                               const float* __restrict__ scales,
                                               float* __restrict__ out) {
  __shared__ __align__(16) u16 lin[10 * 35 * 8];
  __shared__ __align__(16) u16 wt[6144];
  __shared__ float red[128];
  int tid = threadIdx.x;
  int bx = blockIdx.x;
  int owb = (bx & 7) * 32;
  int ohb = ((bx >> 3) & 31) * 8;
  int n = bx >> 8;

  {
    const uint4* src = (const uint4*)wtg;
    for (int i = tid; i < 768; i += 512) ((uint4*)wt)[i] = src[i];
  }
  {
    const u16* src = in_g + (size_t)n * (PDIM * PDIM * 4);
    uint2 z; z.x = 0; z.y = 0;
    for (int i = tid; i < 350; i += 512) {
      int r = i / 35;
      int cx = i - r * 35;
      int gx = owb + cx;
      uint2 v = z;
      if (gx < PDIM) v = *(const uint2*)(src + ((size_t)(ohb + r) * PDIM + gx) * 4);
      *(uint2*)&lin[(r * 35 + cx) * 8] = v;
      *(uint2*)&lin[(r * 35 + cx) * 8 + 4] = z;
    }
  }
  if constexpr (MODE == 0) {
    if (tid < 128) red[tid] = 0.f;
  } else {
    if (tid < 128) red[tid] = scales[tid];
  }
  __syncthreads();

  int w = tid >> 6;
  int l = tid & 63;
  int m = l & 31;
  int h2 = l >> 5;
  f32x16 acc0, acc1;
#pragma unroll
  for (int i = 0; i < 16; ++i) { acc0[i] = 0.f; acc1[i] = 0.f; }

#pragma unroll
  for (int g = 0; g < 6; ++g) {
    int kh = g >> 1, kwp = g & 1;
    bf16x8 a  = *(const bf16x8*)&lin[((w + kh) * 35 + m + kwp * 2 + h2) * 8];
    bf16x8 b0 = *(const bf16x8*)&wt[(2 * g + h2) * 512 + m * 8];
    bf16x8 b1 = *(const bf16x8*)&wt[(2 * g + h2) * 512 + 256 + m * 8];
    if constexpr (MODE == 0) {
      acc0 = __builtin_amdgcn_mfma_f32_32x32x16_bf16(a, b0, acc0, 0, 0, 0);
      acc1 = __builtin_amdgcn_mfma_f32_32x32x16_bf16(a, b1, acc1, 0, 0, 0);
    } else {
      acc0 = __builtin_amdgcn_mfma_f32_32x32x16_bf16(b0, a, acc0, 0, 0, 0);
      acc1 = __builtin_amdgcn_mfma_f32_32x32x16_bf16(b1, a, acc1, 0, 0, 0);
    }
  }

  if constexpr (MODE == 0) {
    float ps0 = 0, pq0 = 0, ps1 = 0, pq1 = 0;
#pragma unroll
    for (int i = 0; i < 16; ++i) {
      ps0 += acc0[i]; pq0 += acc0[i] * acc0[i];
      ps1 += acc1[i]; pq1 += acc1[i] * acc1[i];
    }
    ps0 += __shfl_xor(ps0, 32); pq0 += __shfl_xor(pq0, 32);
    ps1 += __shfl_xor(ps1, 32); pq1 += __shfl_xor(pq1, 32);
    if (h2 == 0) {
      atomicAdd(&red[m], ps0);
      atomicAdd(&red[32 + m], ps1);
      atomicAdd(&red[64 + m], pq0);
      atomicAdd(&red[96 + m], pq1);
    }
    __syncthreads();
    if (tid < 128) atomicAdd(&gstats[(bx & 31) * 128 + tid], red[tid]);
  } else {
    float* op = out + (size_t)n * 64 * 65536 + (size_t)(ohb + w) * 256 + owb + m;
#pragma unroll
    for (int r = 0; r < 16; ++r) {
      int row = (r & 3) + 8 * (r >> 2) + 4 * h2;
      float v0 = acc0[r] * red[row] + red[64 + row];
      __builtin_nontemporal_store(v0 > 0.f ? v0 : 0.f, op + (size_t)row * 65536);
      float v1 = acc1[r] * red[32 + row] + red[96 + row];
      __builtin_nontemporal_store(v1 > 0.f ? v1 : 0.f, op + (size_t)(32 + row) * 65536);
    }
  }
}

// stats (32 replicas each) -> scale/shift. Conv bias cancels in training-mode BN.
__global__ void finalize_kernel(const float* __restrict__ gs,
                                const float* __restrict__ hgam, const float* __restrict__ hbet,
                                const float* __restrict__ lgam, const float* __restrict__ lbet,
                                float* __restrict__ sc) {
  int t = threadIdx.x;   // 128 threads
  const float invP = 1.0f / 1048576.0f;   // 16*256*256
  if (t < 64) {
    float s0 = 0.f, s1 = 0.f;
#pragma unroll 8
    for (int r = 0; r < 32; ++r) { s0 += gs[r * 128 + t]; s1 += gs[r * 128 + 64 + t]; }
    float mean = s0 * invP;
    float var = s1 * invP - mean * mean;
    float s = hgam[t] * rsqrtf(var + 1e-5f);
    sc[t] = s;
    sc[64 + t] = hbet[t] - mean * s;
  } else {
    int c = t - 64;
    const float* g2 = gs + 4096;
    float s0 = 0.f, s1 = 0.f;
#pragma unroll 8
    for (int r = 0; r < 32; ++r) { s0 += g2[r * 128 + c]; s1 += g2[r * 128 + 64 + c]; }
    float mean = s0 * invP;
    float var = s1 * invP - mean * mean;
    float s = lgam[c] * rsqrtf(var + 1e-5f);
    sc[128 + c] = s;
    sc[192 + c] = lbet[c] - mean * s;
  }
}

extern "C" void kernel_launch(void* const* d_in, const int* in_sizes, int n_in,
                              void* d_out, int out_size, void* d_ws, size_t ws_size,
                              hipStream_t stream) {
  const float* x    = (const float*)d_in[0];
  const float* hw   = (const float*)d_in[1];
  const float* hgam = (const float*)d_in[3];
  const float* hbet = (const float*)d_in[4];
  const float* lw   = (const float*)d_in[5];
  const float* lgam = (const float*)d_in[7];
  const float* lbet = (const float*)d_in[8];
  float* out = (float*)d_out;
  float* wsf = (float*)d_ws;

  // ws: [0,16K) hi stats x32 | [16K,32K) lo stats x32 | [32K,+1K) scales |
  //     [33792) wtg_hi 18432B | [52224) wtg_lo 12288B | [65536) hi_g | lo_g
  u16* wtg_hi = (u16*)((char*)d_ws + 33792);
  u16* wtg_lo = (u16*)((char*)d_ws + 52224);
  u16* hi_g   = (u16*)((char*)d_ws + 65536);
  u16* lo_g   = (u16*)((char*)d_ws + 65536 + (size_t)NIMG * PDIM * PDIM * 16 * 2);
  float* scales = wsf + 8192;

  hipMemsetAsync(d_ws, 0, 32768, stream);

  prep_weights<<<1, 512, 0, stream>>>(hw, lw, wtg_hi, wtg_lo);

  int dwt_total = NIMG * PDIM * PDIM;
  dwt_kernel<<<(dwt_total + 255) / 256, 256, 0, stream>>>(x, hi_g, lo_g);

  conv_hi<0><<<4096, 512, 0, stream>>>(hi_g, wtg_hi, wsf, nullptr, nullptr);
  conv_lo<0><<<4096, 512, 0, stream>>>(lo_g, wtg_lo, wsf + 4096, nullptr, nullptr);

  finalize_kernel<<<1, 128, 0, stream>>>(wsf, hgam, hbet, lgam, lbet, scales);

  conv_hi<1><<<4096, 512, 0, stream>>>(hi_g, wtg_hi, nullptr, scales, out);
  conv_lo<1><<<4096, 512, 0, stream>>>(lo_g, wtg_lo, nullptr, scales + 128,
                                       out + (size_t)NIMG * 64 * 65536);
}

// Round 4
// 182.335 us; speedup vs baseline: 2.0997x; 1.1585x over previous
//
#include <hip/hip_runtime.h>

typedef unsigned short u16;
typedef unsigned int   u32;
typedef __attribute__((ext_vector_type(8)))  __bf16 bf16x8;
typedef __attribute__((ext_vector_type(16))) float  f32x16;

#define PDIM 258
#define NIMG 16

static __device__ __forceinline__ u16 f2bf(float f) {
  u32 u = __builtin_bit_cast(u32, f);
  u32 r = u + 0x7FFFu + ((u >> 16) & 1u);
  return (u16)(r >> 16);
}

// ---------------------------------------------------------------------------
// dwt + (block 4161) weight prep & stats zeroing.
// x (16,3,512,512) f32 -> hi_g [16][258][258][16] bf16 (ch0..8 = LH,HL,HH x3)
//                         lo_g [16][258][258][4]  bf16 (ch0..2 = LL)
// wtg_* are bf16 weights in MFMA B-fragment order (linear copy in conv).
// ---------------------------------------------------------------------------
__global__ void dwt_prep(const float* __restrict__ x,
                         u16* __restrict__ hi_g, u16* __restrict__ lo_g,
                         const float* __restrict__ hw, const float* __restrict__ lw,
                         u16* __restrict__ wtg_hi, u16* __restrict__ wtg_lo,
                         float* __restrict__ stats) {
  if (blockIdx.x == 4161) {
    int tid = threadIdx.x;   // 256
    for (int e = tid; e < 9216; e += 256) {
      int t  = e & 7;
      int m  = (e >> 3) & 31;
      int ch = (e >> 8) & 1;
      int gh = e >> 9;              // g*2 + h2
      int h2 = gh & 1, g = gh >> 1;
      int c  = h2 * 8 + t;
      int co = ch * 32 + m;
      float v = 0.f;
      if (c < 9) v = hw[((co * 9 + c) * 3 + g / 3) * 3 + (g % 3)];
      wtg_hi[e] = f2bf(v);
    }
    for (int e = tid; e < 6144; e += 256) {
      int t  = e & 7;
      int m  = (e >> 3) & 31;
      int ch = (e >> 8) & 1;
      int gh = e >> 9;
      int h2 = gh & 1, g = gh >> 1;
      int kh = g >> 1, kw = (g & 1) * 2 + h2;
      int co = ch * 32 + m;
      float v = 0.f;
      if (t < 3 && kw < 3) v = lw[((co * 3 + t) * 3 + kh) * 3 + kw];
      wtg_lo[e] = f2bf(v);
    }
    for (int i = tid; i < 8192; i += 256) stats[i] = 0.f;   // 32 replicas x 128 x {hi,lo}
    return;
  }

  int t = blockIdx.x * 256 + threadIdx.x;
  if (t >= NIMG * PDIM * PDIM) return;
  int px = t % PDIM;
  int ty = t / PDIM;
  int py = ty % PDIM;
  int n  = ty / PDIM;

  u16 hc[16];
  u16 lc[4];
  if (px == 0 || px == PDIM - 1 || py == 0 || py == PDIM - 1) {
#pragma unroll
    for (int i = 0; i < 16; ++i) hc[i] = 0;
#pragma unroll
    for (int i = 0; i < 4; ++i) lc[i] = 0;
  } else {
    int oh = py - 1, ow = px - 1;
#pragma unroll
    for (int c = 0; c < 3; ++c) {
      const float* bp = x + (((size_t)(n * 3 + c) * 512 + 2 * oh) * 512 + 2 * ow);
      float2 r0 = *(const float2*)bp;
      float2 r1 = *(const float2*)(bp + 512);
      float a = r0.x, b = r0.y, cc = r1.x, d = r1.y;
      hc[c]     = f2bf((a + b - cc - d) * 0.5f);
      hc[3 + c] = f2bf((a - b + cc - d) * 0.5f);
      hc[6 + c] = f2bf((a - b - cc + d) * 0.5f);
      lc[c]     = f2bf((a + b + cc + d) * 0.5f);
    }
#pragma unroll
    for (int i = 9; i < 16; ++i) hc[i] = 0;
    lc[3] = 0;
  }
  u32 wds[8];
#pragma unroll
  for (int i = 0; i < 8; ++i) wds[i] = (u32)hc[2 * i] | ((u32)hc[2 * i + 1] << 16);
  uint4 q0; q0.x = wds[0]; q0.y = wds[1]; q0.z = wds[2]; q0.w = wds[3];
  uint4 q1; q1.x = wds[4]; q1.y = wds[5]; q1.z = wds[6]; q1.w = wds[7];
  uint4* hp = (uint4*)(hi_g + (size_t)t * 16);
  hp[0] = q0; hp[1] = q1;
  uint2 ql; ql.x = (u32)lc[0] | ((u32)lc[1] << 16); ql.y = (u32)lc[2] | ((u32)lc[3] << 16);
  *(uint2*)(lo_g + (size_t)t * 4) = ql;
}

// ---------------------------------------------------------------------------
// Merged conv: blocks [0,2048) = hi (Cin 9 pad 16), [2048,4096) = lo (Cin 3 pad 8).
// Block tile 8oh x 64ow, 8 waves; wave w owns oh row, 2 m-tiles x 64 cout.
// hi LDS input: two 8-ch planes [h2][10][66][8] -> A-reads 16B-stride contiguous
// per 16-lane group (round-3 32B-stride pattern was ~2x bank-serialized).
// B-frags reused across both m-tiles: 1.0 LDS reads per MFMA.
// MODE 0: per-channel sum/sumsq -> gstats replica (b&31). MODE 1: BN+ReLU NT store.
// ---------------------------------------------------------------------------
template <int MODE>
__global__ __launch_bounds__(512, 4) void conv_all(const u16* __restrict__ hi_g,
                                                   const u16* __restrict__ lo_g,
                                                   const u16* __restrict__ wtg_hi,
                                                   const u16* __restrict__ wtg_lo,
                                                   float* __restrict__ gstats,
                                                   const float* __restrict__ scales,
                                                   float* __restrict__ out) {
  __shared__ __align__(16) u16 lds[19776];   // hi: lin 10560 + wt 9216 ; lo: lin 5360 + wt 6144
  __shared__ float red[128];
  int tid = threadIdx.x;
  int bx = blockIdx.x;
  bool is_hi = bx < 2048;
  int b = is_hi ? bx : bx - 2048;
  int owb = (b & 3) * 64;
  int ohb = ((b >> 2) & 31) * 8;
  int n = b >> 7;

  if (is_hi) {
    const uint4* wsrc = (const uint4*)wtg_hi;
    uint4* wdst = (uint4*)(lds + 10560);
    for (int i = tid; i < 1152; i += 512) wdst[i] = wsrc[i];
    const u16* src = hi_g + (size_t)n * (PDIM * PDIM * 16);
    for (int i = tid; i < 660; i += 512) {
      int r = i / 66, c = i - r * 66;
      const uint4* g = (const uint4*)(src + ((size_t)(ohb + r) * PDIM + owb + c) * 16);
      uint4 q0 = g[0], q1 = g[1];
      *(uint4*)(lds + ((size_t)(r * 66 + c)) * 8)       = q0;   // plane 0: ch 0-7
      *(uint4*)(lds + ((size_t)(660 + r * 66 + c)) * 8) = q1;   // plane 1: ch 8-15
    }
  } else {
    const uint4* wsrc = (const uint4*)wtg_lo;
    uint4* wdst = (uint4*)(lds + 5360);
    for (int i = tid; i < 768; i += 512) wdst[i] = wsrc[i];
    const u16* src = lo_g + (size_t)n * (PDIM * PDIM * 4);
    uint2 z; z.x = 0; z.y = 0;
    for (int i = tid; i < 670; i += 512) {
      int r = i / 67, c = i - r * 67;
      int gx = owb + c;
      uint2 v = z;
      if (gx < PDIM) v = *(const uint2*)(src + ((size_t)(ohb + r) * PDIM + gx) * 4);
      *(uint2*)(lds + ((size_t)(r * 67 + c)) * 8)     = v;   // ch 0-3
      *(uint2*)(lds + ((size_t)(r * 67 + c)) * 8 + 4) = z;   // ch 4-7 = 0
    }
  }
  if constexpr (MODE == 0) {
    if (tid < 128) red[tid] = 0.f;
  } else {
    if (tid < 128) red[tid] = scales[(is_hi ? 0 : 128) + tid];
  }
  __syncthreads();

  int w = tid >> 6;
  int l = tid & 63;
  int m = l & 31;
  int h2 = l >> 5;
  f32x16 acc0, acc1, acc2, acc3;
#pragma unroll
  for (int i = 0; i < 16; ++i) { acc0[i] = 0.f; acc1[i] = 0.f; acc2[i] = 0.f; acc3[i] = 0.f; }

  if (is_hi) {
    const u16* wt = lds + 10560;
#pragma unroll
    for (int g = 0; g < 9; ++g) {
      int kh = g / 3, kw = g - kh * 3;
      const u16* arow = lds + ((size_t)(h2 * 10 + w + kh) * 66 + m + kw) * 8;
      bf16x8 a0 = *(const bf16x8*)arow;
      bf16x8 a1 = *(const bf16x8*)(arow + 32 * 8);
      bf16x8 b0 = *(const bf16x8*)&wt[(2 * g + h2) * 512 + m * 8];
      bf16x8 b1 = *(const bf16x8*)&wt[(2 * g + h2) * 512 + 256 + m * 8];
      if constexpr (MODE == 0) {
        acc0 = __builtin_amdgcn_mfma_f32_32x32x16_bf16(a0, b0, acc0, 0, 0, 0);
        acc1 = __builtin_amdgcn_mfma_f32_32x32x16_bf16(a0, b1, acc1, 0, 0, 0);
        acc2 = __builtin_amdgcn_mfma_f32_32x32x16_bf16(a1, b0, acc2, 0, 0, 0);
        acc3 = __builtin_amdgcn_mfma_f32_32x32x16_bf16(a1, b1, acc3, 0, 0, 0);
      } else {
        acc0 = __builtin_amdgcn_mfma_f32_32x32x16_bf16(b0, a0, acc0, 0, 0, 0);
        acc1 = __builtin_amdgcn_mfma_f32_32x32x16_bf16(b1, a0, acc1, 0, 0, 0);
        acc2 = __builtin_amdgcn_mfma_f32_32x32x16_bf16(b0, a1, acc2, 0, 0, 0);
        acc3 = __builtin_amdgcn_mfma_f32_32x32x16_bf16(b1, a1, acc3, 0, 0, 0);
      }
    }
  } else {
    const u16* wt = lds + 5360;
#pragma unroll
    for (int g = 0; g < 6; ++g) {
      int kh = g >> 1, kwp = g & 1;
      const u16* arow = lds + ((size_t)(w + kh) * 67 + m + kwp * 2 + h2) * 8;
      bf16x8 a0 = *(const bf16x8*)arow;
      bf16x8 a1 = *(const bf16x8*)(arow + 32 * 8);
      bf16x8 b0 = *(const bf16x8*)&wt[(2 * g + h2) * 512 + m * 8];
      bf16x8 b1 = *(const bf16x8*)&wt[(2 * g + h2) * 512 + 256 + m * 8];
      if constexpr (MODE == 0) {
        acc0 = __builtin_amdgcn_mfma_f32_32x32x16_bf16(a0, b0, acc0, 0, 0, 0);
        acc1 = __builtin_amdgcn_mfma_f32_32x32x16_bf16(a0, b1, acc1, 0, 0, 0);
        acc2 = __builtin_amdgcn_mfma_f32_32x32x16_bf16(a1, b0, acc2, 0, 0, 0);
        acc3 = __builtin_amdgcn_mfma_f32_32x32x16_bf16(a1, b1, acc3, 0, 0, 0);
      } else {
        acc0 = __builtin_amdgcn_mfma_f32_32x32x16_bf16(b0, a0, acc0, 0, 0, 0);
        acc1 = __builtin_amdgcn_mfma_f32_32x32x16_bf16(b1, a0, acc1, 0, 0, 0);
        acc2 = __builtin_amdgcn_mfma_f32_32x32x16_bf16(b0, a1, acc2, 0, 0, 0);
        acc3 = __builtin_amdgcn_mfma_f32_32x32x16_bf16(b1, a1, acc3, 0, 0, 0);
      }
    }
  }

  if constexpr (MODE == 0) {
    float ps0 = 0, pq0 = 0, ps1 = 0, pq1 = 0;
#pragma unroll
    for (int i = 0; i < 16; ++i) {
      ps0 += acc0[i] + acc2[i]; pq0 += acc0[i] * acc0[i] + acc2[i] * acc2[i];
      ps1 += acc1[i] + acc3[i]; pq1 += acc1[i] * acc1[i] + acc3[i] * acc3[i];
    }
    ps0 += __shfl_xor(ps0, 32); pq0 += __shfl_xor(pq0, 32);
    ps1 += __shfl_xor(ps1, 32); pq1 += __shfl_xor(pq1, 32);
    if (h2 == 0) {
      atomicAdd(&red[m], ps0);
      atomicAdd(&red[32 + m], ps1);
      atomicAdd(&red[64 + m], pq0);
      atomicAdd(&red[96 + m], pq1);
    }
    __syncthreads();
    if (tid < 128) atomicAdd(&gstats[(is_hi ? 0 : 4096) + (b & 31) * 128 + tid], red[tid]);
  } else {
    float* op = out + (is_hi ? (size_t)0 : (size_t)NIMG * 64 * 65536)
                    + (size_t)n * 64 * 65536 + (size_t)(ohb + w) * 256 + owb + m;
#pragma unroll
    for (int r = 0; r < 16; ++r) {
      int row = (r & 3) + 8 * (r >> 2) + 4 * h2;
      float sA = red[row], fA = red[64 + row];
      float sB = red[32 + row], fB = red[96 + row];
      float v0 = acc0[r] * sA + fA;
      __builtin_nontemporal_store(v0 > 0.f ? v0 : 0.f, op + (size_t)row * 65536);
      float v1 = acc1[r] * sB + fB;
      __builtin_nontemporal_store(v1 > 0.f ? v1 : 0.f, op + (size_t)(32 + row) * 65536);
      float v2 = acc2[r] * sA + fA;
      __builtin_nontemporal_store(v2 > 0.f ? v2 : 0.f, op + (size_t)row * 65536 + 32);
      float v3 = acc3[r] * sB + fB;
      __builtin_nontemporal_store(v3 > 0.f ? v3 : 0.f, op + (size_t)(32 + row) * 65536 + 32);
    }
  }
}

// stats (32 replicas each) -> scale/shift. Conv bias cancels in training-mode BN.
__global__ void finalize_kernel(const float* __restrict__ gs,
                                const float* __restrict__ hgam, const float* __restrict__ hbet,
                                const float* __restrict__ lgam, const float* __restrict__ lbet,
                                float* __restrict__ sc) {
  int t = threadIdx.x;   // 128 threads
  const float invP = 1.0f / 1048576.0f;   // 16*256*256
  if (t < 64) {
    float s0 = 0.f, s1 = 0.f;
#pragma unroll 8
    for (int r = 0; r < 32; ++r) { s0 += gs[r * 128 + t]; s1 += gs[r * 128 + 64 + t]; }
    float mean = s0 * invP;
    float var = s1 * invP - mean * mean;
    float s = hgam[t] * rsqrtf(var + 1e-5f);
    sc[t] = s;
    sc[64 + t] = hbet[t] - mean * s;
  } else {
    int c = t - 64;
    const float* g2 = gs + 4096;
    float s0 = 0.f, s1 = 0.f;
#pragma unroll 8
    for (int r = 0; r < 32; ++r) { s0 += g2[r * 128 + c]; s1 += g2[r * 128 + 64 + c]; }
    float mean = s0 * invP;
    float var = s1 * invP - mean * mean;
    float s = lgam[c] * rsqrtf(var + 1e-5f);
    sc[128 + c] = s;
    sc[192 + c] = lbet[c] - mean * s;
  }
}

extern "C" void kernel_launch(void* const* d_in, const int* in_sizes, int n_in,
                              void* d_out, int out_size, void* d_ws, size_t ws_size,
                              hipStream_t stream) {
  const float* x    = (const float*)d_in[0];
  const float* hw   = (const float*)d_in[1];
  const float* hgam = (const float*)d_in[3];
  const float* hbet = (const float*)d_in[4];
  const float* lw   = (const float*)d_in[5];
  const float* lgam = (const float*)d_in[7];
  const float* lbet = (const float*)d_in[8];
  float* out = (float*)d_out;
  float* wsf = (float*)d_ws;

  // ws: [0,32K) stats (hi x32 | lo x32) | [32K,33792) scales | wtg_hi 18432B |
  //     [52224) wtg_lo 12288B | [65536) hi_g 34.1MB | lo_g 8.5MB
  u16* wtg_hi = (u16*)((char*)d_ws + 33792);
  u16* wtg_lo = (u16*)((char*)d_ws + 52224);
  u16* hi_g   = (u16*)((char*)d_ws + 65536);
  u16* lo_g   = (u16*)((char*)d_ws + 65536 + (size_t)NIMG * PDIM * PDIM * 16 * 2);
  float* scales = wsf + 8192;

  dwt_prep<<<4162, 256, 0, stream>>>(x, hi_g, lo_g, hw, lw, wtg_hi, wtg_lo, wsf);

  conv_all<0><<<4096, 512, 0, stream>>>(hi_g, lo_g, wtg_hi, wtg_lo, wsf, nullptr, nullptr);

  finalize_kernel<<<1, 128, 0, stream>>>(wsf, hgam, hbet, lgam, lbet, scales);

  conv_all<1><<<4096, 512, 0, stream>>>(hi_g, lo_g, wtg_hi, wtg_lo, nullptr, scales, out);
}

// Round 5
// 173.846 us; speedup vs baseline: 2.2023x; 1.0488x over previous
//
#include <hip/hip_runtime.h>

typedef unsigned short u16;
typedef unsigned int   u32;
typedef __attribute__((ext_vector_type(8)))  __bf16 bf16x8;
typedef __attribute__((ext_vector_type(16))) float  f32x16;

#define NIMG 16

static __device__ __forceinline__ u16 f2bf(float f) {
  u32 u = __builtin_bit_cast(u32, f);
  u32 r = u + 0x7FFFu + ((u >> 16) & 1u);
  return (u16)(r >> 16);
}

// ---------------------------------------------------------------------------
// Prep (1 block): bf16 weights in MFMA B-fragment order + zero stat replicas.
// hi: e = (((g*2+h2)*2 + cohalf)*32 + m)*8 + t ; cin c = h2*8+t (c<9 else 0)
// lo: same shape, g=(kh,kwp); k = h2*8+t -> spatial j=h2, cin c=t
// ---------------------------------------------------------------------------
__global__ void prep_kernel(const float* __restrict__ hw, const float* __restrict__ lw,
                            u16* __restrict__ wtg_hi, u16* __restrict__ wtg_lo,
                            float* __restrict__ stats) {
  int tid = threadIdx.x;   // 512
  for (int e = tid; e < 9216; e += 512) {
    int t  = e & 7;
    int m  = (e >> 3) & 31;
    int ch = (e >> 8) & 1;
    int gh = e >> 9;
    int h2 = gh & 1, g = gh >> 1;
    int c  = h2 * 8 + t;
    int co = ch * 32 + m;
    float v = 0.f;
    if (c < 9) v = hw[((co * 9 + c) * 3 + g / 3) * 3 + (g % 3)];
    wtg_hi[e] = f2bf(v);
  }
  for (int e = tid; e < 6144; e += 512) {
    int t  = e & 7;
    int m  = (e >> 3) & 31;
    int ch = (e >> 8) & 1;
    int gh = e >> 9;
    int h2 = gh & 1, g = gh >> 1;
    int kh = g >> 1, kw = (g & 1) * 2 + h2;
    int co = ch * 32 + m;
    float v = 0.f;
    if (t < 3 && kw < 3) v = lw[((co * 3 + t) * 3 + kh) * 3 + kw];
    wtg_lo[e] = f2bf(v);
  }
  for (int i = tid; i < 8192; i += 512) stats[i] = 0.f;
}

// ---------------------------------------------------------------------------
// Fused DWT+conv: blocks [0,2048) = hi (LH/HL/HH, Cin 9 pad 16), [2048,4096) = lo
// (LL, Cin 3 pad 8). Tile 8oh x 64ow, 8 waves. DWT computed inline from x during
// LDS staging (no materialized subband buffers). hi LDS: two 8-ch planes
// [h2][10][66][8]; lo: [10][67][8]. B-frags reused across 2 m-tiles.
// MODE 0: per-channel sum/sumsq -> gstats replica (b&31).
// MODE 1: per-block BN finalize from gstats, then BN+ReLU non-temporal stores.
// ---------------------------------------------------------------------------
template <int MODE>
__global__ __launch_bounds__(512, 4) void conv_all(const float* __restrict__ x,
                                                   const u16* __restrict__ wtg_hi,
                                                   const u16* __restrict__ wtg_lo,
                                                   float* __restrict__ gstats,
                                                   const float* __restrict__ hgam,
                                                   const float* __restrict__ hbet,
                                                   const float* __restrict__ lgam,
                                                   const float* __restrict__ lbet,
                                                   float* __restrict__ out) {
  __shared__ __align__(16) u16 lds[19776];   // hi: lin 10560 + wt 9216 ; lo: lin 5360 + wt 6144
  __shared__ float red[128];
  int tid = threadIdx.x;
  int bx = blockIdx.x;
  bool is_hi = bx < 2048;
  int b = is_hi ? bx : bx - 2048;
  int owb = (b & 3) * 64;
  int ohb = ((b >> 2) & 31) * 8;
  int n = b >> 7;
  const float* xb = x + (size_t)n * 3 * 262144;

  if (is_hi) {
    const uint4* wsrc = (const uint4*)wtg_hi;
    uint4* wdst = (uint4*)(lds + 10560);
    for (int i = tid; i < 1152; i += 512) wdst[i] = wsrc[i];
    for (int i = tid; i < 660; i += 512) {
      int r = i / 66, c = i - r * 66;
      int gy = ohb - 1 + r;
      int gx = owb - 1 + c;
      u16 hc[9];
      if ((u32)gy < 256u && (u32)gx < 256u) {
#pragma unroll
        for (int ch = 0; ch < 3; ++ch) {
          const float* bp = xb + (size_t)ch * 262144 + (size_t)(2 * gy) * 512 + 2 * gx;
          float2 r0 = *(const float2*)bp;
          float2 r1 = *(const float2*)(bp + 512);
          float t1 = r0.x + r0.y, t2 = r1.x + r1.y;
          float t3 = r0.x - r0.y, t4 = r1.x - r1.y;
          hc[ch]     = f2bf((t1 - t2) * 0.5f);   // LH
          hc[3 + ch] = f2bf((t3 + t4) * 0.5f);   // HL
          hc[6 + ch] = f2bf((t3 - t4) * 0.5f);   // HH
        }
      } else {
#pragma unroll
        for (int j = 0; j < 9; ++j) hc[j] = 0;
      }
      uint4 q0;
      q0.x = (u32)hc[0] | ((u32)hc[1] << 16);
      q0.y = (u32)hc[2] | ((u32)hc[3] << 16);
      q0.z = (u32)hc[4] | ((u32)hc[5] << 16);
      q0.w = (u32)hc[6] | ((u32)hc[7] << 16);
      *(uint4*)(lds + (size_t)(r * 66 + c) * 8) = q0;          // plane 0: ch 0-7
      uint4 q1; q1.x = (u32)hc[8]; q1.y = 0; q1.z = 0; q1.w = 0;
      *(uint4*)(lds + (size_t)(660 + r * 66 + c) * 8) = q1;    // plane 1: ch 8-15
    }
  } else {
    const uint4* wsrc = (const uint4*)wtg_lo;
    uint4* wdst = (uint4*)(lds + 5360);
    for (int i = tid; i < 768; i += 512) wdst[i] = wsrc[i];
    for (int i = tid; i < 670; i += 512) {
      int r = i / 67, c = i - r * 67;
      int gy = ohb - 1 + r;
      int gx = owb - 1 + c;
      u16 lc[3];
      lc[0] = 0; lc[1] = 0; lc[2] = 0;
      if ((u32)gy < 256u && (u32)gx < 256u) {
#pragma unroll
        for (int ch = 0; ch < 3; ++ch) {
          const float* bp = xb + (size_t)ch * 262144 + (size_t)(2 * gy) * 512 + 2 * gx;
          float2 r0 = *(const float2*)bp;
          float2 r1 = *(const float2*)(bp + 512);
          lc[ch] = f2bf((r0.x + r0.y + r1.x + r1.y) * 0.5f);   // LL
        }
      }
      uint4 q;
      q.x = (u32)lc[0] | ((u32)lc[1] << 16);
      q.y = (u32)lc[2];
      q.z = 0; q.w = 0;
      *(uint4*)(lds + (size_t)(r * 67 + c) * 8) = q;
    }
  }

  if constexpr (MODE == 0) {
    if (tid < 128) red[tid] = 0.f;
  } else {
    // per-block BN finalize (folded): channel t handled by thread t<64
    if (tid < 64) {
      const float* gsb = gstats + (is_hi ? 0 : 4096);
      const float* gam = is_hi ? hgam : lgam;
      const float* bet = is_hi ? hbet : lbet;
      float s0 = 0.f, s1 = 0.f;
#pragma unroll 8
      for (int r = 0; r < 32; ++r) { s0 += gsb[r * 128 + tid]; s1 += gsb[r * 128 + 64 + tid]; }
      const float invP = 1.0f / 1048576.0f;   // 16*256*256
      float mean = s0 * invP;
      float var = s1 * invP - mean * mean;
      float s = gam[tid] * rsqrtf(var + 1e-5f);
      red[tid] = s;
      red[64 + tid] = bet[tid] - mean * s;
    }
  }
  __syncthreads();

  int w = tid >> 6;
  int l = tid & 63;
  int m = l & 31;
  int h2 = l >> 5;
  f32x16 acc0, acc1, acc2, acc3;
#pragma unroll
  for (int i = 0; i < 16; ++i) { acc0[i] = 0.f; acc1[i] = 0.f; acc2[i] = 0.f; acc3[i] = 0.f; }

  if (is_hi) {
    const u16* wt = lds + 10560;
#pragma unroll
    for (int g = 0; g < 9; ++g) {
      int kh = g / 3, kw = g - kh * 3;
      const u16* arow = lds + ((size_t)(h2 * 10 + w + kh) * 66 + m + kw) * 8;
      bf16x8 a0 = *(const bf16x8*)arow;
      bf16x8 a1 = *(const bf16x8*)(arow + 32 * 8);
      bf16x8 b0 = *(const bf16x8*)&wt[(2 * g + h2) * 512 + m * 8];
      bf16x8 b1 = *(const bf16x8*)&wt[(2 * g + h2) * 512 + 256 + m * 8];
      if constexpr (MODE == 0) {
        acc0 = __builtin_amdgcn_mfma_f32_32x32x16_bf16(a0, b0, acc0, 0, 0, 0);
        acc1 = __builtin_amdgcn_mfma_f32_32x32x16_bf16(a0, b1, acc1, 0, 0, 0);
        acc2 = __builtin_amdgcn_mfma_f32_32x32x16_bf16(a1, b0, acc2, 0, 0, 0);
        acc3 = __builtin_amdgcn_mfma_f32_32x32x16_bf16(a1, b1, acc3, 0, 0, 0);
      } else {
        acc0 = __builtin_amdgcn_mfma_f32_32x32x16_bf16(b0, a0, acc0, 0, 0, 0);
        acc1 = __builtin_amdgcn_mfma_f32_32x32x16_bf16(b1, a0, acc1, 0, 0, 0);
        acc2 = __builtin_amdgcn_mfma_f32_32x32x16_bf16(b0, a1, acc2, 0, 0, 0);
        acc3 = __builtin_amdgcn_mfma_f32_32x32x16_bf16(b1, a1, acc3, 0, 0, 0);
      }
    }
  } else {
    const u16* wt = lds + 5360;
#pragma unroll
    for (int g = 0; g < 6; ++g) {
      int kh = g >> 1, kwp = g & 1;
      const u16* arow = lds + ((size_t)(w + kh) * 67 + m + kwp * 2 + h2) * 8;
      bf16x8 a0 = *(const bf16x8*)arow;
      bf16x8 a1 = *(const bf16x8*)(arow + 32 * 8);
      bf16x8 b0 = *(const bf16x8*)&wt[(2 * g + h2) * 512 + m * 8];
      bf16x8 b1 = *(const bf16x8*)&wt[(2 * g + h2) * 512 + 256 + m * 8];
      if constexpr (MODE == 0) {
        acc0 = __builtin_amdgcn_mfma_f32_32x32x16_bf16(a0, b0, acc0, 0, 0, 0);
        acc1 = __builtin_amdgcn_mfma_f32_32x32x16_bf16(a0, b1, acc1, 0, 0, 0);
        acc2 = __builtin_amdgcn_mfma_f32_32x32x16_bf16(a1, b0, acc2, 0, 0, 0);
        acc3 = __builtin_amdgcn_mfma_f32_32x32x16_bf16(a1, b1, acc3, 0, 0, 0);
      } else {
        acc0 = __builtin_amdgcn_mfma_f32_32x32x16_bf16(b0, a0, acc0, 0, 0, 0);
        acc1 = __builtin_amdgcn_mfma_f32_32x32x16_bf16(b1, a0, acc1, 0, 0, 0);
        acc2 = __builtin_amdgcn_mfma_f32_32x32x16_bf16(b0, a1, acc2, 0, 0, 0);
        acc3 = __builtin_amdgcn_mfma_f32_32x32x16_bf16(b1, a1, acc3, 0, 0, 0);
      }
    }
  }

  if constexpr (MODE == 0) {
    float ps0 = 0, pq0 = 0, ps1 = 0, pq1 = 0;
#pragma unroll
    for (int i = 0; i < 16; ++i) {
      ps0 += acc0[i] + acc2[i]; pq0 += acc0[i] * acc0[i] + acc2[i] * acc2[i];
      ps1 += acc1[i] + acc3[i]; pq1 += acc1[i] * acc1[i] + acc3[i] * acc3[i];
    }
    ps0 += __shfl_xor(ps0, 32); pq0 += __shfl_xor(pq0, 32);
    ps1 += __shfl_xor(ps1, 32); pq1 += __shfl_xor(pq1, 32);
    if (h2 == 0) {
      atomicAdd(&red[m], ps0);
      atomicAdd(&red[32 + m], ps1);
      atomicAdd(&red[64 + m], pq0);
      atomicAdd(&red[96 + m], pq1);
    }
    __syncthreads();
    if (tid < 128) atomicAdd(&gstats[(is_hi ? 0 : 4096) + (b & 31) * 128 + tid], red[tid]);
  } else {
    float* op = out + (is_hi ? (size_t)0 : (size_t)NIMG * 64 * 65536)
                    + (size_t)n * 64 * 65536 + (size_t)(ohb + w) * 256 + owb + m;
#pragma unroll
    for (int r = 0; r < 16; ++r) {
      int row = (r & 3) + 8 * (r >> 2) + 4 * h2;
      float sA = red[row], fA = red[64 + row];
      float sB = red[32 + row], fB = red[96 + row];
      float v0 = acc0[r] * sA + fA;
      __builtin_nontemporal_store(v0 > 0.f ? v0 : 0.f, op + (size_t)row * 65536);
      float v1 = acc1[r] * sB + fB;
      __builtin_nontemporal_store(v1 > 0.f ? v1 : 0.f, op + (size_t)(32 + row) * 65536);
      float v2 = acc2[r] * sA + fA;
      __builtin_nontemporal_store(v2 > 0.f ? v2 : 0.f, op + (size_t)row * 65536 + 32);
      float v3 = acc3[r] * sB + fB;
      __builtin_nontemporal_store(v3 > 0.f ? v3 : 0.f, op + (size_t)(32 + row) * 65536 + 32);
    }
  }
}

extern "C" void kernel_launch(void* const* d_in, const int* in_sizes, int n_in,
                              void* d_out, int out_size, void* d_ws, size_t ws_size,
                              hipStream_t stream) {
  const float* x    = (const float*)d_in[0];
  const float* hw   = (const float*)d_in[1];
  const float* hgam = (const float*)d_in[3];
  const float* hbet = (const float*)d_in[4];
  const float* lw   = (const float*)d_in[5];
  const float* lgam = (const float*)d_in[7];
  const float* lbet = (const float*)d_in[8];
  float* out = (float*)d_out;
  float* wsf = (float*)d_ws;

  // ws: [0,32K) stats (hi x32 | lo x32) | [33792) wtg_hi 18432B | [52224) wtg_lo 12288B
  u16* wtg_hi = (u16*)((char*)d_ws + 33792);
  u16* wtg_lo = (u16*)((char*)d_ws + 52224);

  prep_kernel<<<1, 512, 0, stream>>>(hw, lw, wtg_hi, wtg_lo, wsf);

  conv_all<0><<<4096, 512, 0, stream>>>(x, wtg_hi, wtg_lo, wsf,
                                        hgam, hbet, lgam, lbet, nullptr);

  conv_all<1><<<4096, 512, 0, stream>>>(x, wtg_hi, wtg_lo, wsf,
                                        hgam, hbet, lgam, lbet, out);
}